// Round 7
// baseline (259.748 us; speedup 1.0000x reference)
//
#include <hip/hip_runtime.h>
#include <hip/hip_bf16.h>
#include <math.h>

#define B_  2
#define T_  2048
#define D_  1024
#define H_  16
#define HD_ 64

typedef __attribute__((ext_vector_type(8))) short short8;
typedef __attribute__((ext_vector_type(4))) float f32x4;

#if __has_builtin(__builtin_amdgcn_exp2f)
#define EXP2F __builtin_amdgcn_exp2f
#else
#define EXP2F exp2f
#endif

__device__ __forceinline__ ushort f2bf(float x) {
    unsigned u = __builtin_bit_cast(unsigned, x);
    return (ushort)((u + 0x7FFFu + ((u >> 16) & 1u)) >> 16);  // RTNE
}

// round-half-up bf16 pair pack
__device__ __forceinline__ unsigned pack_bf2_fast(float a, float b) {
    unsigned ua = __builtin_bit_cast(unsigned, a) + 0x8000u;
    unsigned ub = __builtin_bit_cast(unsigned, b) + 0x8000u;
    return (ua >> 16) | (ub & 0xFFFF0000u);
}

__device__ __forceinline__ void load_lds_16B(const ushort* g, ushort* l) {
    __builtin_amdgcn_global_load_lds(
        (const __attribute__((address_space(1))) unsigned*)g,
        (__attribute__((address_space(3))) unsigned*)l, 16, 0, 0);
}

// ---------------------------------------------------------------------------
// x fp32 -> bf16 (elementwise)
// ---------------------------------------------------------------------------
__global__ __launch_bounds__(256)
void cast_x_kernel(const float* __restrict__ x, ushort* __restrict__ xb, int n4)
{
    int i = blockIdx.x * blockDim.x + threadIdx.x;
    for (; i < n4; i += gridDim.x * blockDim.x) {
        float4 v = ((const float4*)x)[i];
        ushort4 o = { f2bf(v.x), f2bf(v.y), f2bf(v.z), f2bf(v.w) };
        ((ushort4*)xb)[i] = o;
    }
}

// ---------------------------------------------------------------------------
// W[K,M] fp32 -> Wt[M,K] bf16 (64x64 LDS tile transpose)
// ---------------------------------------------------------------------------
__global__ __launch_bounds__(256)
void transpose_cast_w(const float* __restrict__ W, ushort* __restrict__ Wt,
                      int K, int M)
{
    __shared__ ushort Ts[64][65];
    const int m0 = blockIdx.x * 64, k0 = blockIdx.y * 64;
    const int tr = threadIdx.x >> 4;
    const int tc = threadIdx.x & 15;
    #pragma unroll
    for (int it = 0; it < 4; it++) {
        int k = tr + it * 16;
        float4 v = *(const float4*)&W[(size_t)(k0 + k) * M + m0 + tc * 4];
        Ts[tc * 4 + 0][k] = f2bf(v.x);
        Ts[tc * 4 + 1][k] = f2bf(v.y);
        Ts[tc * 4 + 2][k] = f2bf(v.z);
        Ts[tc * 4 + 3][k] = f2bf(v.w);
    }
    __syncthreads();
    const int mr = threadIdx.x >> 2;
    const int c4 = threadIdx.x & 3;
    #pragma unroll
    for (int it = 0; it < 4; it++) {
        int kk = c4 * 16 + it * 4;
        ushort4 o = { Ts[mr][kk], Ts[mr][kk + 1], Ts[mr][kk + 2], Ts[mr][kk + 3] };
        *(ushort4*)&Wt[(size_t)(m0 + mr) * K + k0 + kk] = o;
    }
}

// ---------------------------------------------------------------------------
// bf16 MFMA GEMM: C[N,M] = A[N,K] @ Bt[M,K]^T + bias[M]
// 128 rows x BN cols, BK=64, 256 threads (4 waves, 2 x BN/64... wave grid 2x2),
// 16x16x32 MFMA. MODE 0: fp32 C + bias. MODE 1 (BN=128): QKV epilogue.
// ---------------------------------------------------------------------------
template<int MODE, int BN>
__global__ __launch_bounds__(256)
void mfma_gemm(const ushort* __restrict__ A, const ushort* __restrict__ Bt,
               const float* __restrict__ bias, float* __restrict__ C,
               ushort* __restrict__ Qg, ushort* __restrict__ Kg,
               ushort* __restrict__ Vtg, int K, int M)
{
    constexpr int JT = BN / 64;                 // B col-tiles per wave (2 or 1)
    __shared__ __align__(16) ushort lds[8192 + BN * 64];
    ushort* Asl = lds;
    ushort* Bsl = lds + 8192;

    const int tid = threadIdx.x;
    const int w  = tid >> 6, L = tid & 63;
    const int lt = L & 15, lq = L >> 4;
    const int wr = w >> 1, wc = w & 1;
    const int m0 = blockIdx.x * BN, n0 = blockIdx.y * 128;
    const int rsub = L >> 3;
    const int pgr  = L & 7;

    f32x4 acc[4][2 * JT] = {};

    for (int k0 = 0; k0 < K; k0 += 64) {
        __syncthreads();
        #pragma unroll
        for (int j = 0; j < 4; j++) {
            const int row  = (w * 4 + j) * 8 + rsub;
            const int gran = pgr ^ rsub;
            load_lds_16B(A + (size_t)(n0 + row) * K + k0 + gran * 8,
                         &Asl[row * 64 + pgr * 8]);
        }
        #pragma unroll
        for (int j = 0; j < BN / 32; j++) {
            const int row  = (w * (BN / 32) + j) * 8 + rsub;
            const int gran = pgr ^ rsub;
            load_lds_16B(Bt + (size_t)(m0 + row) * K + k0 + gran * 8,
                         &Bsl[row * 64 + pgr * 8]);
        }
        __syncthreads();

        #pragma unroll
        for (int ks = 0; ks < 2; ks++) {
            short8 af[4], bf[2 * JT];
            #pragma unroll
            for (int i = 0; i < 4; i++) {
                const int ra = wr * 64 + i * 16 + lt;
                af[i] = *(const short8*)&Asl[ra * 64 + (((ks * 4 + lq) ^ (ra & 7)) * 8)];
            }
            #pragma unroll
            for (int j = 0; j < 2 * JT; j++) {
                const int rb = wc * (BN / 2) + j * 16 + lt;
                bf[j] = *(const short8*)&Bsl[rb * 64 + (((ks * 4 + lq) ^ (rb & 7)) * 8)];
            }
            #pragma unroll
            for (int i = 0; i < 4; i++)
                #pragma unroll
                for (int j = 0; j < 2 * JT; j++)
                    acc[i][j] = __builtin_amdgcn_mfma_f32_16x16x32_bf16(af[i], bf[j], acc[i][j], 0, 0, 0);
        }
    }

    if (MODE == 0) {
        #pragma unroll
        for (int j = 0; j < 2 * JT; j++) {
            const int m = m0 + wc * (BN / 2) + j * 16 + lt;
            const float bv = bias[m];
            #pragma unroll
            for (int i = 0; i < 4; i++) {
                const int n = n0 + wr * 64 + i * 16 + lq * 4;
                #pragma unroll
                for (int r = 0; r < 4; r++)
                    C[(size_t)(n + r) * M + m] = acc[i][j][r] + bv;
            }
        }
    } else {
        const int s = m0 >> 10;
        const float qs = (s == 0) ? 0.18033688011112042f : 1.0f;  // 0.125*log2(e)
        #pragma unroll
        for (int j = 0; j < 2 * JT; j++) {
            const int m = m0 + wc * (BN / 2) + j * 16 + lt;
            const float bv = bias[m];
            const int h = (m >> 6) & 15, d = m & 63;
            #pragma unroll
            for (int i = 0; i < 4; i++) {
                const int n = n0 + wr * 64 + i * 16 + lq * 4;
                const int b = n >> 11, t = n & 2047;
                if (s < 2) {
                    ushort* dst = (s == 0 ? Qg : Kg);
                    #pragma unroll
                    for (int r = 0; r < 4; r++)
                        dst[((size_t)(b * H_ + h) * T_ + t + r) * HD_ + d] =
                            f2bf((acc[i][j][r] + bv) * qs);
                } else {
                    ushort4 o = { f2bf(acc[i][j][0] + bv), f2bf(acc[i][j][1] + bv),
                                  f2bf(acc[i][j][2] + bv), f2bf(acc[i][j][3] + bv) };
                    *(ushort4*)&Vtg[((size_t)(b * H_ + h) * HD_ + d) * T_ + t] = o;
                }
            }
        }
    }
}

// ---------------------------------------------------------------------------
// MFMA flash attention v5 — NO K/V LDS, NO barriers.
// S^T formulation means K fragments (A-op: K[key][lq*8..]) and V fragments
// (B-op: Vt[d][key0+lq*8..]) are both 16B-contiguous in GLOBAL memory: load
// them straight into VGPRs. Waves fully independent; only P round-trips
// through 5 KB wave-private LDS. L1/L2 absorb the 4-wave tile redundancy.
// CU-balance: co-resident blocks (stride-256 linear ids) get {x, 31-x} qb.
// ---------------------------------------------------------------------------
__global__ __launch_bounds__(256, 4)
void attn_mfma(const ushort* __restrict__ Qg, const ushort* __restrict__ Kg,
               const ushort* __restrict__ Vtg, ushort* __restrict__ yb)
{
    const int h = blockIdx.y, b = blockIdx.z;
    const int flip = ((blockIdx.y >> 3) ^ blockIdx.z) & 1;
    const int qb = flip ? blockIdx.x : (31 - blockIdx.x);
    const int tid = threadIdx.x;
    const int w  = tid >> 6, L = tid & 63;
    const int lt = L & 15, lq = L >> 4;

    __shared__ __align__(16) ushort Ps[4][16 * 40];   // 5 KB total

    const size_t bh = (size_t)(b * H_ + h);
    const ushort* Qbase  = Qg  + bh * T_ * HD_;
    const ushort* Kf     = Kg  + bh * T_ * HD_ + (size_t)lt * HD_ + lq * 8;   // + key*64
    const ushort* Vf     = Vtg + bh * HD_ * T_ + (size_t)lt * T_  + lq * 8;   // + d16*16*T + key0

    const int q_glob = qb * 64 + w * 16 + lt;
    const short8 qf0 = *(const short8*)(Qbase + (size_t)q_glob * HD_ + lq * 8);
    const short8 qf1 = *(const short8*)(Qbase + (size_t)q_glob * HD_ + 32 + lq * 8);

    f32x4 acc_o[4] = {};
    float lsum = 0.f;
    const int nk = (qb + 2) >> 1;

    for (int kb = 0; kb < nk; kb++) {
        const bool last = (kb == nk - 1);
        const int ksN = (!last || (qb & 1)) ? 4 : 2;
        const int mk0 = last ? ((qb & 1) ? 2 : 0) : 4;

        for (int ks = 0; ks < ksN; ks++) {
            const int key0 = kb * 128 + ks * 32;       // chunk base key
            // ---- K fragments straight from global (16B each) ----
            const ushort* kp = Kf + (size_t)key0 * HD_;
            short8 a00 = *(const short8*)(kp);
            short8 a01 = *(const short8*)(kp + 32);
            short8 a10 = *(const short8*)(kp + 16 * HD_);
            short8 a11 = *(const short8*)(kp + 16 * HD_ + 32);
            // ---- V fragments straight from global ----
            const ushort* vp = Vf + key0;
            short8 vf0 = *(const short8*)(vp);
            short8 vf1 = *(const short8*)(vp + 16 * T_);
            short8 vf2 = *(const short8*)(vp + 32 * T_);
            short8 vf3 = *(const short8*)(vp + 48 * T_);

            f32x4 c0 = {}, c1 = {};
            c0 = __builtin_amdgcn_mfma_f32_16x16x32_bf16(a00, qf0, c0, 0, 0, 0);
            c0 = __builtin_amdgcn_mfma_f32_16x16x32_bf16(a01, qf1, c0, 0, 0, 0);
            c1 = __builtin_amdgcn_mfma_f32_16x16x32_bf16(a10, qf0, c1, 0, 0, 0);
            c1 = __builtin_amdgcn_mfma_f32_16x16x32_bf16(a11, qf1, c1, 0, 0, 0);

            float p[8];
            #pragma unroll
            for (int r = 0; r < 4; r++) { p[r] = EXP2F(c0[r]); p[4 + r] = EXP2F(c1[r]); }
            if (ks >= mk0) {   // diagonal chunk: causal mask
                const int kq = key0 + lq * 4;
                #pragma unroll
                for (int r = 0; r < 4; r++) {
                    if (kq + r > q_glob)      p[r] = 0.f;
                    if (kq + 16 + r > q_glob) p[4 + r] = 0.f;
                }
            }
            lsum += ((p[0] + p[1]) + (p[2] + p[3])) + ((p[4] + p[5]) + (p[6] + p[7]));
            uint2 pk0 = { pack_bf2_fast(p[0], p[1]), pack_bf2_fast(p[2], p[3]) };
            uint2 pk1 = { pack_bf2_fast(p[4], p[5]), pack_bf2_fast(p[6], p[7]) };
            *(uint2*)&Ps[w][lt * 40 + lq * 4]      = pk0;
            *(uint2*)&Ps[w][lt * 40 + 16 + lq * 4] = pk1;

            short8 pf = *(const short8*)&Ps[w][lt * 40 + lq * 8];

            acc_o[0] = __builtin_amdgcn_mfma_f32_16x16x32_bf16(pf, vf0, acc_o[0], 0, 0, 0);
            acc_o[1] = __builtin_amdgcn_mfma_f32_16x16x32_bf16(pf, vf1, acc_o[1], 0, 0, 0);
            acc_o[2] = __builtin_amdgcn_mfma_f32_16x16x32_bf16(pf, vf2, acc_o[2], 0, 0, 0);
            acc_o[3] = __builtin_amdgcn_mfma_f32_16x16x32_bf16(pf, vf3, acc_o[3], 0, 0, 0);
        }
    }

    // ---- deferred row-sum reduction (q = lt, across 4 lq lanes) ----
    lsum += __shfl_xor(lsum, 16, 64);
    lsum += __shfl_xor(lsum, 32, 64);
    const float inv = 1.0f / lsum;

    float linv[4];
    #pragma unroll
    for (int r = 0; r < 4; r++) linv[r] = __shfl(inv, lq * 4 + r, 64);

    ushort* ybase = yb + (size_t)(b * T_ + qb * 64 + w * 16) * D_ + h * HD_;
    #pragma unroll
    for (int r = 0; r < 4; r++)
        #pragma unroll
        for (int dt = 0; dt < 4; dt++)
            ybase[(size_t)(lq * 4 + r) * D_ + dt * 16 + lt] = f2bf(acc_o[dt][r] * linv[r]);
}

// ---------------------------------------------------------------------------
extern "C" void kernel_launch(void* const* d_in, const int* in_sizes, int n_in,
                              void* d_out, int out_size, void* d_ws, size_t ws_size,
                              hipStream_t stream)
{
    const float* x    = (const float*)d_in[0];
    const float* Wqkv = (const float*)d_in[1];
    const float* bqkv = (const float*)d_in[2];
    const float* Wout = (const float*)d_in[3];
    const float* bout = (const float*)d_in[4];
    float* out = (float*)d_out;

    char* ws = (char*)d_ws;
    const size_t NT = (size_t)B_ * T_;
    ushort* xb     = (ushort*)ws;
    ushort* Wqkvt  = (ushort*)(ws + NT * D_ * 2);
    ushort* Woutt  = (ushort*)(ws + NT * D_ * 2 + (size_t)3 * D_ * D_ * 2);
    char*   p      = ws + NT * D_ * 2 + (size_t)4 * D_ * D_ * 2;
    const size_t qkv_elems = (size_t)B_ * H_ * T_ * HD_;
    ushort* Qg  = (ushort*)p;
    ushort* Kg  = (ushort*)(p + qkv_elems * 2);
    ushort* Vtg = (ushort*)(p + qkv_elems * 4);
    ushort* yb  = (ushort*)(p + qkv_elems * 6);

    cast_x_kernel<<<1024, 256, 0, stream>>>(x, xb, (int)(NT * D_ / 4));
    transpose_cast_w<<<dim3(3 * D_ / 64, D_ / 64), 256, 0, stream>>>(Wqkv, Wqkvt, D_, 3 * D_);
    transpose_cast_w<<<dim3(D_ / 64, D_ / 64), 256, 0, stream>>>(Wout, Woutt, D_, D_);

    mfma_gemm<1, 128><<<dim3(3 * D_ / 128, NT / 128), 256, 0, stream>>>(
        xb, Wqkvt, bqkv, nullptr, Qg, Kg, Vtg, D_, 3 * D_);

    attn_mfma<<<dim3(32, H_, B_), 256, 0, stream>>>(Qg, Kg, Vtg, yb);

    mfma_gemm<0, 64><<<dim3(D_ / 64, NT / 128), 256, 0, stream>>>(
        yb, Woutt, bout, out, nullptr, nullptr, nullptr, D_, D_);
}

// Round 8
// 176.670 us; speedup vs baseline: 1.4702x; 1.4702x over previous
//
#include <hip/hip_runtime.h>
#include <hip/hip_bf16.h>
#include <math.h>

#define B_  2
#define T_  2048
#define D_  1024
#define H_  16
#define HD_ 64

typedef __attribute__((ext_vector_type(8))) short short8;
typedef __attribute__((ext_vector_type(4))) float f32x4;

#if __has_builtin(__builtin_amdgcn_exp2f)
#define EXP2F __builtin_amdgcn_exp2f
#else
#define EXP2F exp2f
#endif

__device__ __forceinline__ ushort f2bf(float x) {
    unsigned u = __builtin_bit_cast(unsigned, x);
    return (ushort)((u + 0x7FFFu + ((u >> 16) & 1u)) >> 16);  // RTNE
}

// round-half-up bf16 pair pack
__device__ __forceinline__ unsigned pack_bf2_fast(float a, float b) {
    unsigned ua = __builtin_bit_cast(unsigned, a) + 0x8000u;
    unsigned ub = __builtin_bit_cast(unsigned, b) + 0x8000u;
    return (ua >> 16) | (ub & 0xFFFF0000u);
}

__device__ __forceinline__ void load_lds_16B(const ushort* g, ushort* l) {
    __builtin_amdgcn_global_load_lds(
        (const __attribute__((address_space(1))) unsigned*)g,
        (__attribute__((address_space(3))) unsigned*)l, 16, 0, 0);
}

// ---------------------------------------------------------------------------
// Merged prep: [0,512) cast x->bf16; [512,1280) transpose Wqkv; [1280,1536)
// transpose Wout. Branch is block-uniform.
// ---------------------------------------------------------------------------
__global__ __launch_bounds__(256)
void prep_kernel(const float* __restrict__ x, ushort* __restrict__ xb,
                 const float* __restrict__ Wqkv, ushort* __restrict__ Wqkvt,
                 const float* __restrict__ Wout, ushort* __restrict__ Woutt)
{
    __shared__ ushort Ts[64][65];
    const int bid = blockIdx.x;

    if (bid < 512) {
        const int n4 = (B_ * T_ * D_) / 4;
        for (int i = bid * 256 + threadIdx.x; i < n4; i += 512 * 256) {
            float4 v = ((const float4*)x)[i];
            ushort4 o = { f2bf(v.x), f2bf(v.y), f2bf(v.z), f2bf(v.w) };
            ((ushort4*)xb)[i] = o;
        }
        return;
    }

    const float* W; ushort* Wt; int K, M, m0, k0;
    if (bid < 1280) {
        const int t = bid - 512;           // 48 x 16 tiles
        W = Wqkv; Wt = Wqkvt; K = D_; M = 3 * D_;
        m0 = (t % 48) * 64; k0 = (t / 48) * 64;
    } else {
        const int t = bid - 1280;          // 16 x 16 tiles
        W = Wout; Wt = Woutt; K = D_; M = D_;
        m0 = (t % 16) * 64; k0 = (t / 16) * 64;
    }

    const int tr = threadIdx.x >> 4;
    const int tc = threadIdx.x & 15;
    #pragma unroll
    for (int it = 0; it < 4; it++) {
        int k = tr + it * 16;
        float4 v = *(const float4*)&W[(size_t)(k0 + k) * M + m0 + tc * 4];
        Ts[tc * 4 + 0][k] = f2bf(v.x);
        Ts[tc * 4 + 1][k] = f2bf(v.y);
        Ts[tc * 4 + 2][k] = f2bf(v.z);
        Ts[tc * 4 + 3][k] = f2bf(v.w);
    }
    __syncthreads();
    const int mr = threadIdx.x >> 2;
    const int c4 = threadIdx.x & 3;
    #pragma unroll
    for (int it = 0; it < 4; it++) {
        int kk = c4 * 16 + it * 4;
        ushort4 o = { Ts[mr][kk], Ts[mr][kk + 1], Ts[mr][kk + 2], Ts[mr][kk + 3] };
        *(ushort4*)&Wt[(size_t)(m0 + mr) * K + k0 + kk] = o;
    }
}

// ---------------------------------------------------------------------------
// bf16 MFMA GEMM: C[N,M] = A[N,K] @ Bt[M,K]^T + bias[M]
// BM=128 rows x BN=64 cols, BK=64, 256 threads (waves 2x2: wr=row-half,
// wc=32-col half), 16x16x32 MFMA, 4x2 acc tiles per wave. 24 KB LDS ->
// up to 6 blocks/CU co-resident (this kernel is latency-bound at short K;
// block parallelism is the lever, not tile AI).
// MODE 0: fp32 C + bias.  MODE 1: QKV epilogue (bf16 Q*cscale, K [b,h,t,d];
// Vt [b,h,d,t]) — Q pre-scaled by 0.125*log2(e).
// ---------------------------------------------------------------------------
template<int MODE>
__global__ __launch_bounds__(256, 4)
void mfma_gemm(const ushort* __restrict__ A, const ushort* __restrict__ Bt,
               const float* __restrict__ bias, float* __restrict__ C,
               ushort* __restrict__ Qg, ushort* __restrict__ Kg,
               ushort* __restrict__ Vtg, int K, int M)
{
    __shared__ __align__(16) ushort lds[8192 + 4096];   // A 128x64 | B 64x64
    ushort* Asl = lds;
    ushort* Bsl = lds + 8192;

    const int tid = threadIdx.x;
    const int w  = tid >> 6, L = tid & 63;
    const int lt = L & 15, lq = L >> 4;
    const int wr = w >> 1, wc = w & 1;
    const int m0 = blockIdx.x * 64, n0 = blockIdx.y * 128;
    const int rsub = L >> 3;
    const int pgr  = L & 7;

    f32x4 acc[4][2] = {};

    for (int k0 = 0; k0 < K; k0 += 64) {
        __syncthreads();
        #pragma unroll
        for (int j = 0; j < 4; j++) {
            const int row  = (w * 4 + j) * 8 + rsub;
            const int gran = pgr ^ rsub;
            load_lds_16B(A + (size_t)(n0 + row) * K + k0 + gran * 8,
                         &Asl[row * 64 + pgr * 8]);
        }
        #pragma unroll
        for (int j = 0; j < 2; j++) {
            const int row  = (w * 2 + j) * 8 + rsub;
            const int gran = pgr ^ rsub;
            load_lds_16B(Bt + (size_t)(m0 + row) * K + k0 + gran * 8,
                         &Bsl[row * 64 + pgr * 8]);
        }
        __syncthreads();

        #pragma unroll
        for (int ks = 0; ks < 2; ks++) {
            short8 af[4], bf[2];
            #pragma unroll
            for (int i = 0; i < 4; i++) {
                const int ra = wr * 64 + i * 16 + lt;
                af[i] = *(const short8*)&Asl[ra * 64 + (((ks * 4 + lq) ^ (ra & 7)) * 8)];
            }
            #pragma unroll
            for (int j = 0; j < 2; j++) {
                const int rb = wc * 32 + j * 16 + lt;
                bf[j] = *(const short8*)&Bsl[rb * 64 + (((ks * 4 + lq) ^ (rb & 7)) * 8)];
            }
            #pragma unroll
            for (int i = 0; i < 4; i++)
                #pragma unroll
                for (int j = 0; j < 2; j++)
                    acc[i][j] = __builtin_amdgcn_mfma_f32_16x16x32_bf16(af[i], bf[j], acc[i][j], 0, 0, 0);
        }
    }

    if (MODE == 0) {
        #pragma unroll
        for (int j = 0; j < 2; j++) {
            const int m = m0 + wc * 32 + j * 16 + lt;
            const float bv = bias[m];
            #pragma unroll
            for (int i = 0; i < 4; i++) {
                const int n = n0 + wr * 64 + i * 16 + lq * 4;
                #pragma unroll
                for (int r = 0; r < 4; r++)
                    C[(size_t)(n + r) * M + m] = acc[i][j][r] + bv;
            }
        }
    } else {
        const int s = m0 >> 10;           // block-uniform (m0 multiple of 64)
        const float qs = (s == 0) ? 0.18033688011112042f : 1.0f;  // 0.125*log2(e)
        #pragma unroll
        for (int j = 0; j < 2; j++) {
            const int m = m0 + wc * 32 + j * 16 + lt;
            const float bv = bias[m];
            const int h = (m >> 6) & 15, d = m & 63;
            #pragma unroll
            for (int i = 0; i < 4; i++) {
                const int n = n0 + wr * 64 + i * 16 + lq * 4;
                const int b = n >> 11, t = n & 2047;
                if (s < 2) {
                    ushort* dst = (s == 0 ? Qg : Kg);
                    #pragma unroll
                    for (int r = 0; r < 4; r++)
                        dst[((size_t)(b * H_ + h) * T_ + t + r) * HD_ + d] =
                            f2bf((acc[i][j][r] + bv) * qs);
                } else {
                    ushort4 o = { f2bf(acc[i][j][0] + bv), f2bf(acc[i][j][1] + bv),
                                  f2bf(acc[i][j][2] + bv), f2bf(acc[i][j][3] + bv) };
                    *(ushort4*)&Vtg[((size_t)(b * H_ + h) * HD_ + d) * T_ + t] = o;
                }
            }
        }
    }
}

// ---------------------------------------------------------------------------
// MFMA flash attention v4 (round-6 known-good).
// One 64-q-row tile per block (1024 blocks). CU-balance: co-resident blocks
// (stride-256 linear ids) get {x, 31-x} via flip = (y>>3)^z.
// S^T via mfma(kf,qf); scalar lsum; packed b64 P writes; no online max
// (logits bounded; raw v_exp_f32). Hot kb iterations unmasked; final masked.
// ---------------------------------------------------------------------------
__global__ __launch_bounds__(256, 4)
void attn_mfma(const ushort* __restrict__ Qg, const ushort* __restrict__ Kg,
               const ushort* __restrict__ Vtg, ushort* __restrict__ yb)
{
    const int h = blockIdx.y, b = blockIdx.z;
    const int flip = ((blockIdx.y >> 3) ^ blockIdx.z) & 1;
    const int qb = flip ? blockIdx.x : (31 - blockIdx.x);
    const int tid = threadIdx.x;
    const int w  = tid >> 6, L = tid & 63;
    const int lt = L & 15, lq = L >> 4;
    const int kswz = lt & 7;

    __shared__ __align__(16) ushort Ks [128 * 64];   // 16 KB
    __shared__ __align__(16) ushort Vts[64 * 128];   // 16 KB
    __shared__ __align__(16) ushort Ps [4][16 * 40]; // 5 KB

    const size_t bh = (size_t)(b * H_ + h);
    const ushort* Qbase  = Qg  + bh * T_ * HD_;
    const ushort* Kbase  = Kg  + bh * T_ * HD_;
    const ushort* Vtbase = Vtg + bh * HD_ * T_;

    const int q_glob = qb * 64 + w * 16 + lt;
    const short8 qf0 = *(const short8*)(Qbase + (size_t)q_glob * HD_ + lq * 8);
    const short8 qf1 = *(const short8*)(Qbase + (size_t)q_glob * HD_ + 32 + lq * 8);

    f32x4 acc_o[4] = {};
    float lsum = 0.f;

    const int krow = tid >> 3, kpg = tid & 7;
    const int vrow = tid >> 4, vpg = tid & 15;
    const int nk = (qb + 2) >> 1;

    for (int kb = 0; kb < nk; kb++) {
        __syncthreads();
        #pragma unroll
        for (int rr = 0; rr < 4; rr++) {
            const int row = krow + 32 * rr;
            load_lds_16B(Kbase + (size_t)(kb * 128 + row) * HD_ + (kpg ^ (row & 7)) * 8,
                         &Ks[row * 64 + kpg * 8]);
        }
        #pragma unroll
        for (int rr = 0; rr < 4; rr++) {
            const int d = vrow + 16 * rr;
            load_lds_16B(Vtbase + (size_t)d * T_ + kb * 128 + (vpg ^ (d & 7)) * 8,
                         &Vts[d * 128 + vpg * 8]);
        }
        __syncthreads();

        if (kb < nk - 1) {
            // ---------------- hot path: no masking ----------------
            #pragma unroll
            for (int ks = 0; ks < 4; ks++) {
                const int row0 = (2 * ks) * 16 + lt;
                const int row1 = row0 + 16;
                short8 a00 = *(const short8*)&Ks[row0 * 64 + ((lq ^ kswz) * 8)];
                short8 a01 = *(const short8*)&Ks[row0 * 64 + (((4 + lq) ^ kswz) * 8)];
                short8 a10 = *(const short8*)&Ks[row1 * 64 + ((lq ^ kswz) * 8)];
                short8 a11 = *(const short8*)&Ks[row1 * 64 + (((4 + lq) ^ kswz) * 8)];
                f32x4 c0 = {}, c1 = {};
                c0 = __builtin_amdgcn_mfma_f32_16x16x32_bf16(a00, qf0, c0, 0, 0, 0);
                c0 = __builtin_amdgcn_mfma_f32_16x16x32_bf16(a01, qf1, c0, 0, 0, 0);
                c1 = __builtin_amdgcn_mfma_f32_16x16x32_bf16(a10, qf0, c1, 0, 0, 0);
                c1 = __builtin_amdgcn_mfma_f32_16x16x32_bf16(a11, qf1, c1, 0, 0, 0);

                float p0 = EXP2F(c0[0]), p1 = EXP2F(c0[1]);
                float p2 = EXP2F(c0[2]), p3 = EXP2F(c0[3]);
                float p4 = EXP2F(c1[0]), p5 = EXP2F(c1[1]);
                float p6 = EXP2F(c1[2]), p7 = EXP2F(c1[3]);
                lsum += ((p0 + p1) + (p2 + p3)) + ((p4 + p5) + (p6 + p7));
                uint2 pk0 = { pack_bf2_fast(p0, p1), pack_bf2_fast(p2, p3) };
                uint2 pk1 = { pack_bf2_fast(p4, p5), pack_bf2_fast(p6, p7) };
                *(uint2*)&Ps[w][lt * 40 + lq * 4]      = pk0;
                *(uint2*)&Ps[w][lt * 40 + 16 + lq * 4] = pk1;

                short8 pf = *(const short8*)&Ps[w][lt * 40 + lq * 8];

                #pragma unroll
                for (int dt = 0; dt < 4; dt++) {
                    const int vr = dt * 16 + lt;
                    short8 vf = *(const short8*)&Vts[vr * 128 + (((ks * 4 + lq) ^ kswz) * 8)];
                    acc_o[dt] = __builtin_amdgcn_mfma_f32_16x16x32_bf16(pf, vf, acc_o[dt], 0, 0, 0);
                }
            }
        } else {
            // ---------------- final kb: causal masking ----------------
            const int ksN = (qb & 1) ? 4 : 2;
            const int mk0 = (qb & 1) ? 2 : 0;
            for (int ks = 0; ks < ksN; ks++) {
                const int row0 = (2 * ks) * 16 + lt;
                const int row1 = row0 + 16;
                short8 a00 = *(const short8*)&Ks[row0 * 64 + ((lq ^ kswz) * 8)];
                short8 a01 = *(const short8*)&Ks[row0 * 64 + (((4 + lq) ^ kswz) * 8)];
                short8 a10 = *(const short8*)&Ks[row1 * 64 + ((lq ^ kswz) * 8)];
                short8 a11 = *(const short8*)&Ks[row1 * 64 + (((4 + lq) ^ kswz) * 8)];
                f32x4 c0 = {}, c1 = {};
                c0 = __builtin_amdgcn_mfma_f32_16x16x32_bf16(a00, qf0, c0, 0, 0, 0);
                c0 = __builtin_amdgcn_mfma_f32_16x16x32_bf16(a01, qf1, c0, 0, 0, 0);
                c1 = __builtin_amdgcn_mfma_f32_16x16x32_bf16(a10, qf0, c1, 0, 0, 0);
                c1 = __builtin_amdgcn_mfma_f32_16x16x32_bf16(a11, qf1, c1, 0, 0, 0);

                float p[8];
                #pragma unroll
                for (int r = 0; r < 4; r++) { p[r] = EXP2F(c0[r]); p[4 + r] = EXP2F(c1[r]); }
                if (ks >= mk0) {
                    const int key0 = kb * 128 + (2 * ks) * 16 + lq * 4;
                    #pragma unroll
                    for (int r = 0; r < 4; r++) {
                        if (key0 + r > q_glob)      p[r] = 0.f;
                        if (key0 + 16 + r > q_glob) p[4 + r] = 0.f;
                    }
                }
                lsum += ((p[0] + p[1]) + (p[2] + p[3])) + ((p[4] + p[5]) + (p[6] + p[7]));
                uint2 pk0 = { pack_bf2_fast(p[0], p[1]), pack_bf2_fast(p[2], p[3]) };
                uint2 pk1 = { pack_bf2_fast(p[4], p[5]), pack_bf2_fast(p[6], p[7]) };
                *(uint2*)&Ps[w][lt * 40 + lq * 4]      = pk0;
                *(uint2*)&Ps[w][lt * 40 + 16 + lq * 4] = pk1;

                short8 pf = *(const short8*)&Ps[w][lt * 40 + lq * 8];

                #pragma unroll
                for (int dt = 0; dt < 4; dt++) {
                    const int vr = dt * 16 + lt;
                    short8 vf = *(const short8*)&Vts[vr * 128 + (((ks * 4 + lq) ^ kswz) * 8)];
                    acc_o[dt] = __builtin_amdgcn_mfma_f32_16x16x32_bf16(pf, vf, acc_o[dt], 0, 0, 0);
                }
            }
        }
    }

    // ---- deferred row-sum reduction (q = lt, across 4 lq lanes) ----
    lsum += __shfl_xor(lsum, 16, 64);
    lsum += __shfl_xor(lsum, 32, 64);
    const float inv = 1.0f / lsum;

    float linv[4];
    #pragma unroll
    for (int r = 0; r < 4; r++) linv[r] = __shfl(inv, lq * 4 + r, 64);

    ushort* ybase = yb + (size_t)(b * T_ + qb * 64 + w * 16) * D_ + h * HD_;
    #pragma unroll
    for (int r = 0; r < 4; r++)
        #pragma unroll
        for (int dt = 0; dt < 4; dt++)
            ybase[(size_t)(lq * 4 + r) * D_ + dt * 16 + lt] = f2bf(acc_o[dt][r] * linv[r]);
}

// ---------------------------------------------------------------------------
extern "C" void kernel_launch(void* const* d_in, const int* in_sizes, int n_in,
                              void* d_out, int out_size, void* d_ws, size_t ws_size,
                              hipStream_t stream)
{
    const float* x    = (const float*)d_in[0];
    const float* Wqkv = (const float*)d_in[1];
    const float* bqkv = (const float*)d_in[2];
    const float* Wout = (const float*)d_in[3];
    const float* bout = (const float*)d_in[4];
    float* out = (float*)d_out;

    char* ws = (char*)d_ws;
    const size_t NT = (size_t)B_ * T_;
    ushort* xb     = (ushort*)ws;
    ushort* Wqkvt  = (ushort*)(ws + NT * D_ * 2);
    ushort* Woutt  = (ushort*)(ws + NT * D_ * 2 + (size_t)3 * D_ * D_ * 2);
    char*   p      = ws + NT * D_ * 2 + (size_t)4 * D_ * D_ * 2;
    const size_t qkv_elems = (size_t)B_ * H_ * T_ * HD_;
    ushort* Qg  = (ushort*)p;
    ushort* Kg  = (ushort*)(p + qkv_elems * 2);
    ushort* Vtg = (ushort*)(p + qkv_elems * 4);
    ushort* yb  = (ushort*)(p + qkv_elems * 6);

    // prep: x cast + both weight transposes in one launch
    prep_kernel<<<1536, 256, 0, stream>>>(x, xb, Wqkv, Wqkvt, Wout, Woutt);

    // 1) QKV GEMM (128x64 tiles, 1536 blocks = 6/CU)
    mfma_gemm<1><<<dim3(3 * D_ / 64, NT / 128), 256, 0, stream>>>(
        xb, Wqkvt, bqkv, nullptr, Qg, Kg, Vtg, D_, 3 * D_);

    // 2) flash causal attention -> bf16 y
    attn_mfma<<<dim3(32, H_, B_), 256, 0, stream>>>(Qg, Kg, Vtg, yb);

    // 3) out = y @ Wout + bout (128x64 tiles, 512 blocks)
    mfma_gemm<0><<<dim3(D_ / 64, NT / 128), 256, 0, stream>>>(
        yb, Woutt, bout, out, nullptr, nullptr, nullptr, D_, D_);
}

// Round 9
// 168.939 us; speedup vs baseline: 1.5375x; 1.0458x over previous
//
#include <hip/hip_runtime.h>
#include <hip/hip_bf16.h>
#include <math.h>

#define B_  2
#define T_  2048
#define D_  1024
#define H_  16
#define HD_ 64

typedef __attribute__((ext_vector_type(8))) short short8;
typedef __attribute__((ext_vector_type(4))) float f32x4;

#if __has_builtin(__builtin_amdgcn_exp2f)
#define EXP2F __builtin_amdgcn_exp2f
#else
#define EXP2F exp2f
#endif

__device__ __forceinline__ ushort f2bf(float x) {
    unsigned u = __builtin_bit_cast(unsigned, x);
    return (ushort)((u + 0x7FFFu + ((u >> 16) & 1u)) >> 16);  // RTNE
}

// round-half-up bf16 pair pack
__device__ __forceinline__ unsigned pack_bf2_fast(float a, float b) {
    unsigned ua = __builtin_bit_cast(unsigned, a) + 0x8000u;
    unsigned ub = __builtin_bit_cast(unsigned, b) + 0x8000u;
    return (ua >> 16) | (ub & 0xFFFF0000u);
}

__device__ __forceinline__ void load_lds_16B(const ushort* g, ushort* l) {
    __builtin_amdgcn_global_load_lds(
        (const __attribute__((address_space(1))) unsigned*)g,
        (__attribute__((address_space(3))) unsigned*)l, 16, 0, 0);
}

// ---------------------------------------------------------------------------
// Merged prep: [0,512) cast x->bf16; [512,1280) transpose Wqkv; [1280,1536)
// transpose Wout. Wt stores are 16B/lane (full-line coalesced).
// ---------------------------------------------------------------------------
__global__ __launch_bounds__(256)
void prep_kernel(const float* __restrict__ x, ushort* __restrict__ xb,
                 const float* __restrict__ Wqkv, ushort* __restrict__ Wqkvt,
                 const float* __restrict__ Wout, ushort* __restrict__ Woutt)
{
    __shared__ ushort Ts[64][65];
    const int bid = blockIdx.x;

    if (bid < 512) {
        const int n4 = (B_ * T_ * D_) / 4;
        for (int i = bid * 256 + threadIdx.x; i < n4; i += 512 * 256) {
            float4 v = ((const float4*)x)[i];
            ushort4 o = { f2bf(v.x), f2bf(v.y), f2bf(v.z), f2bf(v.w) };
            ((ushort4*)xb)[i] = o;
        }
        return;
    }

    const float* W; ushort* Wt; int K, M, m0, k0;
    if (bid < 1280) {
        const int t = bid - 512;           // 48 x 16 tiles
        W = Wqkv; Wt = Wqkvt; K = D_; M = 3 * D_;
        m0 = (t % 48) * 64; k0 = (t / 48) * 64;
    } else {
        const int t = bid - 1280;          // 16 x 16 tiles
        W = Wout; Wt = Woutt; K = D_; M = D_;
        m0 = (t % 16) * 64; k0 = (t / 16) * 64;
    }

    const int tr = threadIdx.x >> 4;
    const int tc = threadIdx.x & 15;
    #pragma unroll
    for (int it = 0; it < 4; it++) {
        int k = tr + it * 16;
        float4 v = *(const float4*)&W[(size_t)(k0 + k) * M + m0 + tc * 4];
        Ts[tc * 4 + 0][k] = f2bf(v.x);
        Ts[tc * 4 + 1][k] = f2bf(v.y);
        Ts[tc * 4 + 2][k] = f2bf(v.z);
        Ts[tc * 4 + 3][k] = f2bf(v.w);
    }
    __syncthreads();
    #pragma unroll
    for (int it = 0; it < 2; it++) {
        const int mr  = (threadIdx.x >> 3) + it * 32;
        const int seg = (threadIdx.x & 7) * 8;
        short8 v;
        #pragma unroll
        for (int r = 0; r < 8; r++) v[r] = (short)Ts[mr][seg + r];
        *(short8*)&Wt[(size_t)(m0 + mr) * K + k0 + seg] = v;
    }
}

// ---------------------------------------------------------------------------
// QKV GEMM: qkv = x @ WqkvT^T + b. 128x128 tile, BK=64, 4 waves (2x2),
// 4x4 16x16x32 MFMA per wave (best LDS-read : MFMA ratio). Epilogue
// round-trips acc through the 32 KB staging LDS to emit fully-coalesced
// 16B/lane stores: Q,K [b,h,t,d] (Q pre-scaled by 0.125*log2e), Vt [b,h,d,t].
// ---------------------------------------------------------------------------
__global__ __launch_bounds__(256, 4)
void gemm_qkv(const ushort* __restrict__ A, const ushort* __restrict__ Bt,
              const float* __restrict__ bias,
              ushort* __restrict__ Qg, ushort* __restrict__ Kg,
              ushort* __restrict__ Vtg)
{
    const int K = D_;
    __shared__ __align__(16) ushort lds[16384];   // staging, reused by epilogue
    ushort* Asl = lds;
    ushort* Bsl = lds + 8192;

    const int tid = threadIdx.x;
    const int w  = tid >> 6, L = tid & 63;
    const int lt = L & 15, lq = L >> 4;
    const int wr = w >> 1, wc = w & 1;
    const int m0 = blockIdx.x * 128, n0 = blockIdx.y * 128;
    const int rsub = L >> 3;
    const int pgr  = L & 7;

    f32x4 acc[4][4] = {};

    for (int k0 = 0; k0 < K; k0 += 64) {
        __syncthreads();
        #pragma unroll
        for (int j = 0; j < 4; j++) {
            const int row  = (w * 4 + j) * 8 + rsub;
            const int gran = pgr ^ rsub;
            load_lds_16B(A  + (size_t)(n0 + row) * K + k0 + gran * 8,
                         &Asl[row * 64 + pgr * 8]);
            load_lds_16B(Bt + (size_t)(m0 + row) * K + k0 + gran * 8,
                         &Bsl[row * 64 + pgr * 8]);
        }
        __syncthreads();

        #pragma unroll
        for (int ks = 0; ks < 2; ks++) {
            short8 af[4], bf[4];
            #pragma unroll
            for (int i = 0; i < 4; i++) {
                const int ra = wr * 64 + i * 16 + lt;
                af[i] = *(const short8*)&Asl[ra * 64 + (((ks * 4 + lq) ^ (ra & 7)) * 8)];
                const int rb = wc * 64 + i * 16 + lt;
                bf[i] = *(const short8*)&Bsl[rb * 64 + (((ks * 4 + lq) ^ (rb & 7)) * 8)];
            }
            #pragma unroll
            for (int i = 0; i < 4; i++)
                #pragma unroll
                for (int j = 0; j < 4; j++)
                    acc[i][j] = __builtin_amdgcn_mfma_f32_16x16x32_bf16(af[i], bf[j], acc[i][j], 0, 0, 0);
        }
    }

    __syncthreads();   // staging reads complete; reuse lds for epilogue
    const int s  = m0 >> 10;                       // block-uniform
    const int h0 = (m0 & 1023) >> 6;               // first of 2 heads
    const float qs = (s == 0) ? 0.18033688011112042f : 1.0f;   // 0.125*log2(e)

    if (s < 2) {
        // LDS[n][m] bf16 (stride 128); scalar writes are lane-consecutive in m
        #pragma unroll
        for (int j = 0; j < 4; j++) {
            const int m  = wc * 64 + j * 16 + lt;
            const float bv = bias[m0 + m];
            #pragma unroll
            for (int i = 0; i < 4; i++) {
                const int n = wr * 64 + i * 16 + lq * 4;
                #pragma unroll
                for (int r = 0; r < 4; r++)
                    lds[(n + r) * 128 + m] = f2bf((acc[i][j][r] + bv) * qs);
            }
        }
        __syncthreads();
        ushort* dst = (s == 0 ? Qg : Kg);
        #pragma unroll
        for (int it = 0; it < 8; it++) {
            const int g   = tid + it * 256;        // 0..2047
            const int row = g >> 4, c = g & 15;
            const int n = n0 + row;
            const int b = n >> 11, t = n & 2047;
            const int h = h0 + (c >> 3), d = (c & 7) * 8;
            short8 v = *(const short8*)&lds[row * 128 + c * 8];
            *(short8*)&dst[((size_t)(b * H_ + h) * T_ + t) * HD_ + d] = v;
        }
    } else {
        // LDS[m][n] bf16 (stride 128); packed b64 along n (r-consecutive)
        #pragma unroll
        for (int j = 0; j < 4; j++) {
            const int m  = wc * 64 + j * 16 + lt;
            const float bv = bias[m0 + m];
            #pragma unroll
            for (int i = 0; i < 4; i++) {
                const int n = wr * 64 + i * 16 + lq * 4;
                uint2 pk = { pack_bf2_fast(acc[i][j][0] + bv, acc[i][j][1] + bv),
                             pack_bf2_fast(acc[i][j][2] + bv, acc[i][j][3] + bv) };
                *(uint2*)&lds[m * 128 + n] = pk;
            }
        }
        __syncthreads();
        const int b = n0 >> 11, t0 = n0 & 2047;
        #pragma unroll
        for (int it = 0; it < 8; it++) {
            const int g   = tid + it * 256;
            const int row = g >> 4, c = g & 15;    // row = m, c = t-chunk
            const int h = h0 + (row >> 6), d = row & 63;
            short8 v = *(const short8*)&lds[row * 128 + c * 8];
            *(short8*)&Vtg[((size_t)(b * H_ + h) * HD_ + d) * T_ + t0 + c * 8] = v;
        }
    }
}

// ---------------------------------------------------------------------------
// Out GEMM: out = y @ WoutT^T + b. 128n x 64m tile, 512 blocks. MFMA operands
// SWAPPED (A-op = W m-rows, B-op = y n-rows) so D's reg quad = 4 consecutive
// m -> direct float4 stores, no LDS round trip.
// ---------------------------------------------------------------------------
__global__ __launch_bounds__(256, 4)
void gemm_out(const ushort* __restrict__ A, const ushort* __restrict__ Bt,
              const float* __restrict__ bias, float* __restrict__ C)
{
    const int K = D_, M = D_;
    __shared__ __align__(16) ushort lds[8192 + 4096];   // y 128x64 | W 64x64
    ushort* Asl = lds;
    ushort* Bsl = lds + 8192;

    const int tid = threadIdx.x;
    const int w  = tid >> 6, L = tid & 63;
    const int lt = L & 15, lq = L >> 4;
    const int wr = w >> 1, wc = w & 1;
    const int m0 = blockIdx.x * 64, n0 = blockIdx.y * 128;
    const int rsub = L >> 3;
    const int pgr  = L & 7;

    f32x4 acc[2][4] = {};   // [m-tile][n-tile]

    for (int k0 = 0; k0 < K; k0 += 64) {
        __syncthreads();
        #pragma unroll
        for (int j = 0; j < 4; j++) {
            const int row  = (w * 4 + j) * 8 + rsub;
            const int gran = pgr ^ rsub;
            load_lds_16B(A + (size_t)(n0 + row) * K + k0 + gran * 8,
                         &Asl[row * 64 + pgr * 8]);
        }
        #pragma unroll
        for (int j = 0; j < 2; j++) {
            const int row  = (w * 2 + j) * 8 + rsub;
            const int gran = pgr ^ rsub;
            load_lds_16B(Bt + (size_t)(m0 + row) * K + k0 + gran * 8,
                         &Bsl[row * 64 + pgr * 8]);
        }
        __syncthreads();

        #pragma unroll
        for (int ks = 0; ks < 2; ks++) {
            short8 wf[2], yf[4];
            #pragma unroll
            for (int j = 0; j < 2; j++) {
                const int rb = wc * 32 + j * 16 + lt;
                wf[j] = *(const short8*)&Bsl[rb * 64 + (((ks * 4 + lq) ^ (rb & 7)) * 8)];
            }
            #pragma unroll
            for (int i = 0; i < 4; i++) {
                const int ra = wr * 64 + i * 16 + lt;
                yf[i] = *(const short8*)&Asl[ra * 64 + (((ks * 4 + lq) ^ (ra & 7)) * 8)];
            }
            #pragma unroll
            for (int j = 0; j < 2; j++)
                #pragma unroll
                for (int i = 0; i < 4; i++)
                    acc[j][i] = __builtin_amdgcn_mfma_f32_16x16x32_bf16(wf[j], yf[i], acc[j][i], 0, 0, 0);
        }
    }

    // D layout: row (lq*4+r) = m within tile, col (lt) = n within tile
    #pragma unroll
    for (int j = 0; j < 2; j++) {
        const int mbase = m0 + wc * 32 + j * 16 + lq * 4;
        const float4 bv = *(const float4*)&bias[mbase];
        #pragma unroll
        for (int i = 0; i < 4; i++) {
            const int n = n0 + wr * 64 + i * 16 + lt;
            float4 o = { acc[j][i][0] + bv.x, acc[j][i][1] + bv.y,
                         acc[j][i][2] + bv.z, acc[j][i][3] + bv.w };
            *(float4*)&C[(size_t)n * M + mbase] = o;
        }
    }
}

// ---------------------------------------------------------------------------
// MFMA flash attention v4 (round-6/8 known-good, unchanged).
// ---------------------------------------------------------------------------
__global__ __launch_bounds__(256, 4)
void attn_mfma(const ushort* __restrict__ Qg, const ushort* __restrict__ Kg,
               const ushort* __restrict__ Vtg, ushort* __restrict__ yb)
{
    const int h = blockIdx.y, b = blockIdx.z;
    const int flip = ((blockIdx.y >> 3) ^ blockIdx.z) & 1;
    const int qb = flip ? blockIdx.x : (31 - blockIdx.x);
    const int tid = threadIdx.x;
    const int w  = tid >> 6, L = tid & 63;
    const int lt = L & 15, lq = L >> 4;
    const int kswz = lt & 7;

    __shared__ __align__(16) ushort Ks [128 * 64];
    __shared__ __align__(16) ushort Vts[64 * 128];
    __shared__ __align__(16) ushort Ps [4][16 * 40];

    const size_t bh = (size_t)(b * H_ + h);
    const ushort* Qbase  = Qg  + bh * T_ * HD_;
    const ushort* Kbase  = Kg  + bh * T_ * HD_;
    const ushort* Vtbase = Vtg + bh * HD_ * T_;

    const int q_glob = qb * 64 + w * 16 + lt;
    const short8 qf0 = *(const short8*)(Qbase + (size_t)q_glob * HD_ + lq * 8);
    const short8 qf1 = *(const short8*)(Qbase + (size_t)q_glob * HD_ + 32 + lq * 8);

    f32x4 acc_o[4] = {};
    float lsum = 0.f;

    const int krow = tid >> 3, kpg = tid & 7;
    const int vrow = tid >> 4, vpg = tid & 15;
    const int nk = (qb + 2) >> 1;

    for (int kb = 0; kb < nk; kb++) {
        __syncthreads();
        #pragma unroll
        for (int rr = 0; rr < 4; rr++) {
            const int row = krow + 32 * rr;
            load_lds_16B(Kbase + (size_t)(kb * 128 + row) * HD_ + (kpg ^ (row & 7)) * 8,
                         &Ks[row * 64 + kpg * 8]);
        }
        #pragma unroll
        for (int rr = 0; rr < 4; rr++) {
            const int d = vrow + 16 * rr;
            load_lds_16B(Vtbase + (size_t)d * T_ + kb * 128 + (vpg ^ (d & 7)) * 8,
                         &Vts[d * 128 + vpg * 8]);
        }
        __syncthreads();

        if (kb < nk - 1) {
            #pragma unroll
            for (int ks = 0; ks < 4; ks++) {
                const int row0 = (2 * ks) * 16 + lt;
                const int row1 = row0 + 16;
                short8 a00 = *(const short8*)&Ks[row0 * 64 + ((lq ^ kswz) * 8)];
                short8 a01 = *(const short8*)&Ks[row0 * 64 + (((4 + lq) ^ kswz) * 8)];
                short8 a10 = *(const short8*)&Ks[row1 * 64 + ((lq ^ kswz) * 8)];
                short8 a11 = *(const short8*)&Ks[row1 * 64 + (((4 + lq) ^ kswz) * 8)];
                f32x4 c0 = {}, c1 = {};
                c0 = __builtin_amdgcn_mfma_f32_16x16x32_bf16(a00, qf0, c0, 0, 0, 0);
                c0 = __builtin_amdgcn_mfma_f32_16x16x32_bf16(a01, qf1, c0, 0, 0, 0);
                c1 = __builtin_amdgcn_mfma_f32_16x16x32_bf16(a10, qf0, c1, 0, 0, 0);
                c1 = __builtin_amdgcn_mfma_f32_16x16x32_bf16(a11, qf1, c1, 0, 0, 0);

                float p0 = EXP2F(c0[0]), p1 = EXP2F(c0[1]);
                float p2 = EXP2F(c0[2]), p3 = EXP2F(c0[3]);
                float p4 = EXP2F(c1[0]), p5 = EXP2F(c1[1]);
                float p6 = EXP2F(c1[2]), p7 = EXP2F(c1[3]);
                lsum += ((p0 + p1) + (p2 + p3)) + ((p4 + p5) + (p6 + p7));
                uint2 pk0 = { pack_bf2_fast(p0, p1), pack_bf2_fast(p2, p3) };
                uint2 pk1 = { pack_bf2_fast(p4, p5), pack_bf2_fast(p6, p7) };
                *(uint2*)&Ps[w][lt * 40 + lq * 4]      = pk0;
                *(uint2*)&Ps[w][lt * 40 + 16 + lq * 4] = pk1;

                short8 pf = *(const short8*)&Ps[w][lt * 40 + lq * 8];

                #pragma unroll
                for (int dt = 0; dt < 4; dt++) {
                    const int vr = dt * 16 + lt;
                    short8 vf = *(const short8*)&Vts[vr * 128 + (((ks * 4 + lq) ^ kswz) * 8)];
                    acc_o[dt] = __builtin_amdgcn_mfma_f32_16x16x32_bf16(pf, vf, acc_o[dt], 0, 0, 0);
                }
            }
        } else {
            const int ksN = (qb & 1) ? 4 : 2;
            const int mk0 = (qb & 1) ? 2 : 0;
            for (int ks = 0; ks < ksN; ks++) {
                const int row0 = (2 * ks) * 16 + lt;
                const int row1 = row0 + 16;
                short8 a00 = *(const short8*)&Ks[row0 * 64 + ((lq ^ kswz) * 8)];
                short8 a01 = *(const short8*)&Ks[row0 * 64 + (((4 + lq) ^ kswz) * 8)];
                short8 a10 = *(const short8*)&Ks[row1 * 64 + ((lq ^ kswz) * 8)];
                short8 a11 = *(const short8*)&Ks[row1 * 64 + (((4 + lq) ^ kswz) * 8)];
                f32x4 c0 = {}, c1 = {};
                c0 = __builtin_amdgcn_mfma_f32_16x16x32_bf16(a00, qf0, c0, 0, 0, 0);
                c0 = __builtin_amdgcn_mfma_f32_16x16x32_bf16(a01, qf1, c0, 0, 0, 0);
                c1 = __builtin_amdgcn_mfma_f32_16x16x32_bf16(a10, qf0, c1, 0, 0, 0);
                c1 = __builtin_amdgcn_mfma_f32_16x16x32_bf16(a11, qf1, c1, 0, 0, 0);

                float p[8];
                #pragma unroll
                for (int r = 0; r < 4; r++) { p[r] = EXP2F(c0[r]); p[4 + r] = EXP2F(c1[r]); }
                if (ks >= mk0) {
                    const int key0 = kb * 128 + (2 * ks) * 16 + lq * 4;
                    #pragma unroll
                    for (int r = 0; r < 4; r++) {
                        if (key0 + r > q_glob)      p[r] = 0.f;
                        if (key0 + 16 + r > q_glob) p[4 + r] = 0.f;
                    }
                }
                lsum += ((p[0] + p[1]) + (p[2] + p[3])) + ((p[4] + p[5]) + (p[6] + p[7]));
                uint2 pk0 = { pack_bf2_fast(p[0], p[1]), pack_bf2_fast(p[2], p[3]) };
                uint2 pk1 = { pack_bf2_fast(p[4], p[5]), pack_bf2_fast(p[6], p[7]) };
                *(uint2*)&Ps[w][lt * 40 + lq * 4]      = pk0;
                *(uint2*)&Ps[w][lt * 40 + 16 + lq * 4] = pk1;

                short8 pf = *(const short8*)&Ps[w][lt * 40 + lq * 8];

                #pragma unroll
                for (int dt = 0; dt < 4; dt++) {
                    const int vr = dt * 16 + lt;
                    short8 vf = *(const short8*)&Vts[vr * 128 + (((ks * 4 + lq) ^ kswz) * 8)];
                    acc_o[dt] = __builtin_amdgcn_mfma_f32_16x16x32_bf16(pf, vf, acc_o[dt], 0, 0, 0);
                }
            }
        }
    }

    lsum += __shfl_xor(lsum, 16, 64);
    lsum += __shfl_xor(lsum, 32, 64);
    const float inv = 1.0f / lsum;

    float linv[4];
    #pragma unroll
    for (int r = 0; r < 4; r++) linv[r] = __shfl(inv, lq * 4 + r, 64);

    ushort* ybase = yb + (size_t)(b * T_ + qb * 64 + w * 16) * D_ + h * HD_;
    #pragma unroll
    for (int r = 0; r < 4; r++)
        #pragma unroll
        for (int dt = 0; dt < 4; dt++)
            ybase[(size_t)(lq * 4 + r) * D_ + dt * 16 + lt] = f2bf(acc_o[dt][r] * linv[r]);
}

// ---------------------------------------------------------------------------
extern "C" void kernel_launch(void* const* d_in, const int* in_sizes, int n_in,
                              void* d_out, int out_size, void* d_ws, size_t ws_size,
                              hipStream_t stream)
{
    const float* x    = (const float*)d_in[0];
    const float* Wqkv = (const float*)d_in[1];
    const float* bqkv = (const float*)d_in[2];
    const float* Wout = (const float*)d_in[3];
    const float* bout = (const float*)d_in[4];
    float* out = (float*)d_out;

    char* ws = (char*)d_ws;
    const size_t NT = (size_t)B_ * T_;
    ushort* xb     = (ushort*)ws;
    ushort* Wqkvt  = (ushort*)(ws + NT * D_ * 2);
    ushort* Woutt  = (ushort*)(ws + NT * D_ * 2 + (size_t)3 * D_ * D_ * 2);
    char*   p      = ws + NT * D_ * 2 + (size_t)4 * D_ * D_ * 2;
    const size_t qkv_elems = (size_t)B_ * H_ * T_ * HD_;
    ushort* Qg  = (ushort*)p;
    ushort* Kg  = (ushort*)(p + qkv_elems * 2);
    ushort* Vtg = (ushort*)(p + qkv_elems * 4);
    ushort* yb  = (ushort*)(p + qkv_elems * 6);

    prep_kernel<<<1536, 256, 0, stream>>>(x, xb, Wqkv, Wqkvt, Wout, Woutt);

    gemm_qkv<<<dim3(3 * D_ / 128, NT / 128), 256, 0, stream>>>(
        xb, Wqkvt, bqkv, Qg, Kg, Vtg);

    attn_mfma<<<dim3(32, H_, B_), 256, 0, stream>>>(Qg, Kg, Vtg, yb);

    gemm_out<<<dim3(D_ / 64, NT / 128), 256, 0, stream>>>(
        yb, Woutt, bout, out);
}